// Round 1
// baseline (670.896 us; speedup 1.0000x reference)
//
#include <hip/hip_runtime.h>

#define K_CLUSTERS 512
#define FDIM 64
#define TILE_K 128

// Transpose W [F=64][K=512] -> Wt [K][F], and wsq[k] = sum_f W[f][k]^2 (fp32).
// wsq summation order differs from numpy's but its delta (~1e-11) only matters
// via a ulp(64) boundary crossing in the final add -- negligible flip risk.
__global__ __launch_bounds__(64) void vq_prep(const float* __restrict__ W,
                                              float* __restrict__ Wt,
                                              float* __restrict__ wsq) {
    int k = blockIdx.x;   // 0..511
    int f = threadIdx.x;  // 0..63
    float w = W[f * K_CLUSTERS + k];
    Wt[k * FDIM + f] = w;
    float s = w * w;
#pragma unroll
    for (int off = 32; off > 0; off >>= 1) s += __shfl_xor(s, off, 64);
    if (f == 0) wsq[k] = s;
}

// One row per thread. Replicates np fp32 rounding structure:
//   d = fl( fl(sumz - 2*dot) + wsq )   via fmaf(-2, dot, sumz) + wsq
// (2*dot is exact in fp32, so single-rounded fma == np's two-step form).
__global__ __launch_bounds__(256) void vq_main(const float* __restrict__ z,
                                               const float* __restrict__ Wt,
                                               const float* __restrict__ wsq,
                                               float* __restrict__ out_zq,
                                               float* __restrict__ out_idx,
                                               float* __restrict__ out_diff) {
    __shared__ float sW[TILE_K][68];  // pad 64->68 (16B-aligned rows)
    __shared__ float swsq[TILE_K];
    int i = blockIdx.x * 256 + threadIdx.x;

    float zr[FDIM];
    const float4* z4 = (const float4*)(z + (size_t)i * FDIM);
#pragma unroll
    for (int f4 = 0; f4 < 16; f4++) {
        float4 v = z4[f4];
        zr[4 * f4 + 0] = v.x; zr[4 * f4 + 1] = v.y;
        zr[4 * f4 + 2] = v.z; zr[4 * f4 + 3] = v.w;
    }

    // sumz: replicate numpy pairwise sum (8-accumulator unroll, tree combine),
    // contraction off so products are individually fp32-rounded like np's z*z.
    float sumz;
    {
#pragma clang fp contract(off)
        float r0 = zr[0] * zr[0], r1 = zr[1] * zr[1], r2 = zr[2] * zr[2], r3 = zr[3] * zr[3];
        float r4 = zr[4] * zr[4], r5 = zr[5] * zr[5], r6 = zr[6] * zr[6], r7 = zr[7] * zr[7];
#pragma unroll
        for (int b = 8; b < 64; b += 8) {
            r0 += zr[b + 0] * zr[b + 0]; r1 += zr[b + 1] * zr[b + 1];
            r2 += zr[b + 2] * zr[b + 2]; r3 += zr[b + 3] * zr[b + 3];
            r4 += zr[b + 4] * zr[b + 4]; r5 += zr[b + 5] * zr[b + 5];
            r6 += zr[b + 6] * zr[b + 6]; r7 += zr[b + 7] * zr[b + 7];
        }
        sumz = ((r0 + r1) + (r2 + r3)) + ((r4 + r5) + (r6 + r7));
    }

    float dmin = 3.0e38f;
    int kmin = 0;

    for (int t = 0; t < K_CLUSTERS / TILE_K; t++) {
        __syncthreads();
        int base = t * TILE_K;
        // cooperative stage of Wt tile
        for (int u = threadIdx.x; u < TILE_K * 16; u += 256) {
            int kk = u >> 4, f4 = u & 15;
            float4 v = *(const float4*)(Wt + (size_t)(base + kk) * FDIM + f4 * 4);
            *(float4*)(&sW[kk][f4 * 4]) = v;
        }
        if (threadIdx.x < TILE_K) swsq[threadIdx.x] = wsq[base + threadIdx.x];
        __syncthreads();

#pragma unroll 2
        for (int k = 0; k < TILE_K; k++) {
            float dot = 0.0f;
#pragma unroll
            for (int f = 0; f < FDIM; f++) dot = fmaf(zr[f], sW[k][f], dot);
            float d = fmaf(-2.0f, dot, sumz) + swsq[k];
            if (d < dmin) { dmin = d; kmin = base + k; }  // strict < => first-index ties, like np.argmin
        }
    }

    out_idx[i] = (float)kmin;

    // Epilogue replicates np fp32 exactly:
    //   d1 = fl(w - z); diff = fl(d1*d1); z_q = fl(z + d1)
    const float4* wrow = (const float4*)(Wt + (size_t)kmin * FDIM);
    float4* zq4 = (float4*)(out_zq + (size_t)i * FDIM);
    float4* df4 = (float4*)(out_diff + (size_t)i * FDIM);
#pragma unroll
    for (int f4 = 0; f4 < 16; f4++) {
        float4 wv = wrow[f4];
        float4 zq, df;
        {
#pragma clang fp contract(off)
            float d1x = wv.x - zr[4 * f4 + 0]; zq.x = zr[4 * f4 + 0] + d1x; df.x = d1x * d1x;
            float d1y = wv.y - zr[4 * f4 + 1]; zq.y = zr[4 * f4 + 1] + d1y; df.y = d1y * d1y;
            float d1z = wv.z - zr[4 * f4 + 2]; zq.z = zr[4 * f4 + 2] + d1z; df.z = d1z * d1z;
            float d1w = wv.w - zr[4 * f4 + 3]; zq.w = zr[4 * f4 + 3] + d1w; df.w = d1w * d1w;
        }
        zq4[f4] = zq;
        df4[f4] = df;
    }
}

// One-hot: fully coalesced float4 writes; 128 consecutive threads share a row.
__global__ __launch_bounds__(256) void vq_onehot(const float* __restrict__ idxf,
                                                 float* __restrict__ enc) {
    long long tid = (long long)blockIdx.x * 256 + threadIdx.x;  // over N*128 float4s
    int row = (int)(tid >> 7);
    int f4 = (int)(tid & 127);
    int kk = (int)idxf[row];
    int c = kk - f4 * 4;  // 0..3 if the hot column is in this chunk
    float4 v;
    v.x = (c == 0) ? 1.0f : 0.0f;
    v.y = (c == 1) ? 1.0f : 0.0f;
    v.z = (c == 2) ? 1.0f : 0.0f;
    v.w = (c == 3) ? 1.0f : 0.0f;
    ((float4*)enc)[tid] = v;
}

extern "C" void kernel_launch(void* const* d_in, const int* in_sizes, int n_in,
                              void* d_out, int out_size, void* d_ws, size_t ws_size,
                              hipStream_t stream) {
    const float* z = (const float*)d_in[0];  // [N,64] fp32
    const float* W = (const float*)d_in[1];  // [64,512] fp32
    int N = in_sizes[0] / FDIM;              // 131072

    float* out = (float*)d_out;
    float* out_zq = out;                                   // N*64
    float* out_idx = out_zq + (size_t)N * FDIM;            // N
    float* enc = out_idx + N;                              // N*512
    float* out_diff = enc + (size_t)N * K_CLUSTERS;        // N*64

    float* Wt = (float*)d_ws;                 // 512*64 floats
    float* wsq = Wt + K_CLUSTERS * FDIM;      // 512 floats

    vq_prep<<<K_CLUSTERS, 64, 0, stream>>>(W, Wt, wsq);
    vq_main<<<N / 256, 256, 0, stream>>>(z, Wt, wsq, out_zq, out_idx, out_diff);
    long long total4 = (long long)N * (K_CLUSTERS / 4);
    vq_onehot<<<(int)(total4 / 256), 256, 0, stream>>>(out_idx, enc);
}